// Round 10
// baseline (81.988 us; speedup 1.0000x reference)
//
#include <hip/hip_runtime.h>
#include <hip/hip_bf16.h>

// Causal attention, B=2 H=16 S=2048 D=64, fp32 in/out.
// R10 = R9 + (a) V fragments loaded DIRECTLY from global (permuted V^T in ws)
// into registers -- deletes all V LDS reads + V staging (LDS pipe was the
// most-loaded shared resource: 80KB -> 40KB per block-tile), LDS 32->16KB;
// (b) paired q-tiles (31-py, py) processed sequentially per block: every
// block = exactly 33 tile-visits, grid 512, zero drain tail.
// Swapped QK^T, in-register softmax (exp2 native, defer-max), MFMA-based l
// (ones column), permlane max-reduce, setprio, 2-phase K double buffer.

typedef __attribute__((ext_vector_type(8))) short bf16x8;
typedef __attribute__((ext_vector_type(4))) float f32x4;
typedef unsigned uint2v __attribute__((ext_vector_type(2)));

#define MFMA32K(a, b, c) __builtin_amdgcn_mfma_f32_16x16x32_bf16(a, b, c, 0, 0, 0)

constexpr int Bsz = 2, Hn = 16, Sn = 2048, Dn = 64;
constexpr int QBLK = 64, KBLK = 64;
constexpr int NE = Bsz * Hn * Sn * Dn;

#if defined(__has_builtin)
#if __has_builtin(__builtin_amdgcn_exp2f)
#define EXP2(x) __builtin_amdgcn_exp2f(x)
#endif
#endif
#ifndef EXP2
#define EXP2(x) exp2f(x)
#endif

__device__ inline short f2bf(float f) {
  union { float f; unsigned u; } v;
  v.f = f;
  unsigned r = v.u + 0x7FFF + ((v.u >> 16) & 1);  // RNE
  return (short)(r >> 16);
}

__device__ inline unsigned pk_bf16(float lo, float hi) {
  unsigned r;
  asm("v_cvt_pk_bf16_f32 %0, %1, %2" : "=v"(r) : "v"(lo), "v"(hi));
  return r;
}

__device__ inline void gl2lds16(const void* g, void* l) {
  __builtin_amdgcn_global_load_lds(
      (const __attribute__((address_space(1))) unsigned int*)g,
      (__attribute__((address_space(3))) unsigned int*)l, 16, 0, 0);
}

// K tile rows = 128B; XOR 16B-slot index with row&7 (involution, both sides)
__device__ inline int swz(int row, int colbyte) {
  return row * 128 + (colbyte ^ ((row & 7) << 4));
}

#if defined(__has_builtin)
#if __has_builtin(__builtin_amdgcn_permlane16_swap) && \
    __has_builtin(__builtin_amdgcn_permlane32_swap)
#define HAVE_PERMLANE_SWAP 1
#endif
#endif

__device__ inline float xred_max(float x) {
#ifdef HAVE_PERMLANE_SWAP
  uint2v a = __builtin_amdgcn_permlane16_swap(__float_as_uint(x),
                                              __float_as_uint(x), false, false);
  x = fmaxf(__uint_as_float(a[0]), __uint_as_float(a[1]));
  uint2v b = __builtin_amdgcn_permlane32_swap(__float_as_uint(x),
                                              __float_as_uint(x), false, false);
  x = fmaxf(__uint_as_float(b[0]), __uint_as_float(b[1]));
#else
  x = fmaxf(x, __shfl_xor(x, 16, 64));
  x = fmaxf(x, __shfl_xor(x, 32, 64));
#endif
  return x;
}

// ------- prepass (merged): z=0: K fp32->bf16; z=1: V -> V^T bf16 -------
// V^T columns permuted within each 64-tile: position p holds element
// k(p) = 32*(p>>5) + 16*((p>>2)&1) + 4*((p>>3)&3) + (p&3), so the PV
// A-fragment {k=32t2+4g+i} u {k=32t2+16+4g+i} is contiguous 16B at p=32t2+8g.
__global__ __launch_bounds__(256) void prep(const float* __restrict__ K,
                                            const float* __restrict__ V,
                                            short* __restrict__ Kb,
                                            short* __restrict__ Vt) {
  const int tile = blockIdx.x, bh = blockIdx.y;
  const int tid = threadIdx.x;
  const int r = tid >> 2, c = (tid & 3) * 16;
  const size_t base = (size_t)bh * Sn * Dn;

  if (blockIdx.z == 0) {
    const float* kp = K + base + (size_t)(tile * 64 + r) * Dn + c;
    float4 x0 = *(const float4*)(kp + 0);
    float4 x1 = *(const float4*)(kp + 4);
    float4 x2 = *(const float4*)(kp + 8);
    float4 x3 = *(const float4*)(kp + 12);
    bf16x8 w0, w1;
    w0[0] = f2bf(x0.x); w0[1] = f2bf(x0.y); w0[2] = f2bf(x0.z); w0[3] = f2bf(x0.w);
    w0[4] = f2bf(x1.x); w0[5] = f2bf(x1.y); w0[6] = f2bf(x1.z); w0[7] = f2bf(x1.w);
    w1[0] = f2bf(x2.x); w1[1] = f2bf(x2.y); w1[2] = f2bf(x2.z); w1[3] = f2bf(x2.w);
    w1[4] = f2bf(x3.x); w1[5] = f2bf(x3.y); w1[6] = f2bf(x3.z); w1[7] = f2bf(x3.w);
    short* op = Kb + base + (size_t)(tile * 64 + r) * Dn + c;
    *(bf16x8*)op = w0;
    *(bf16x8*)(op + 8) = w1;
  } else {
    __shared__ short t[64][66];  // +2 pad
    const float* vp = V + base + (size_t)(tile * 64 + r) * Dn + c;
    float4 x0 = *(const float4*)(vp + 0);
    float4 x1 = *(const float4*)(vp + 4);
    float4 x2 = *(const float4*)(vp + 8);
    float4 x3 = *(const float4*)(vp + 12);
    short* tr = &t[r][c];
    tr[0] = f2bf(x0.x); tr[1] = f2bf(x0.y); tr[2] = f2bf(x0.z); tr[3] = f2bf(x0.w);
    tr[4] = f2bf(x1.x); tr[5] = f2bf(x1.y); tr[6] = f2bf(x1.z); tr[7] = f2bf(x1.w);
    tr[8] = f2bf(x2.x); tr[9] = f2bf(x2.y); tr[10] = f2bf(x2.z); tr[11] = f2bf(x2.w);
    tr[12] = f2bf(x3.x); tr[13] = f2bf(x3.y); tr[14] = f2bf(x3.z); tr[15] = f2bf(x3.w);
    __syncthreads();
    short* op = Vt + base + (size_t)r * Sn + tile * 64 + c;
    bf16x8 w0, w1;
#pragma unroll
    for (int j = 0; j < 8; ++j) {
      int p0 = c + j, p1 = c + 8 + j;
      int k0 = 32 * (p0 >> 5) + 16 * ((p0 >> 2) & 1) + 4 * ((p0 >> 3) & 3) + (p0 & 3);
      int k1 = 32 * (p1 >> 5) + 16 * ((p1 >> 2) & 1) + 4 * ((p1 >> 3) & 3) + (p1 & 3);
      w0[j] = t[k0][r];
      w1[j] = t[k1][r];
    }
    *(bf16x8*)op = w0;
    *(bf16x8*)(op + 8) = w1;
  }
}

// ---------------------------- main attention ----------------------------
// block (bh, py): processes q-tiles qtA = 31-py then qtB = py sequentially
// (nA + nB = 33 tile-visits for every block -> perfect balance, no drain).
__global__ __launch_bounds__(256, 2) void attn_fwd(
    const float* __restrict__ Q, const short* __restrict__ Kb,
    const short* __restrict__ Vt, const float* __restrict__ SF,
    float* __restrict__ O) {
  __shared__ short Kbuf[2][64 * 64];   // [k][d] bf16, swizzled (16 KB)

  const int bh = blockIdx.x;
  const int py = blockIdx.y;           // 0..15
  const int qtA = 31 - py, qtB = py;
  const int nA = qtA + 1, nTot = nA + qtB + 1;

  const int tid = threadIdx.x;
  const int wave = tid >> 6, lane = tid & 63;
  const int g = lane >> 4, lc = lane & 15;
  const float qscale = 1.4426950408889634f / SF[0];  // exp2 domain

  const size_t base = (size_t)bh * Sn * Dn;
  const char* Kg = (const char*)(Kb + base);

  // hoisted per-lane K fragment LDS offsets
  int ka[4][2];
#pragma unroll
  for (int t = 0; t < 4; ++t) {
    ka[t][0] = swz(t * 16 + lc, g * 16);
    ka[t][1] = swz(t * 16 + lc, g * 16 + 64);
  }
  // hoisted K staging source offsets (within one 8KB tile)
  int koff[2];
#pragma unroll
  for (int j = 0; j < 2; ++j) {
    int c = (wave * 2 + j) * 1024 + lane * 16;
    int row = c >> 7;
    koff[j] = row * 128 + ((c & 127) ^ ((row & 7) << 4));
  }
  // V^T per-lane global row bases (permuted layout; 16B frag per (t2,dt))
  const char* vb[4];
#pragma unroll
  for (int dt = 0; dt < 4; ++dt)
    vb[dt] = (const char*)(Vt + base) + (size_t)(dt * 16 + lc) * (Sn * 2) + g * 16;

  auto stageK = [&](int kt, int buf) {
    const char* src = Kg + ((size_t)kt << 13);
#pragma unroll
    for (int j = 0; j < 2; ++j)
      gl2lds16(src + koff[j], (char*)Kbuf[buf] + (wave * 2 + j) * 1024);
  };

  auto loadQ = [&](int qg, bf16x8* bq) {
    const float* qp = Q + base + (size_t)qg * Dn + g * 8;
#pragma unroll
    for (int h = 0; h < 2; ++h) {
      float4 x0 = *(const float4*)(qp + 32 * h);
      float4 x1 = *(const float4*)(qp + 32 * h + 4);
      bf16x8 a;
      a[0] = f2bf(x0.x * qscale); a[1] = f2bf(x0.y * qscale);
      a[2] = f2bf(x0.z * qscale); a[3] = f2bf(x0.w * qscale);
      a[4] = f2bf(x1.x * qscale); a[5] = f2bf(x1.y * qscale);
      a[6] = f2bf(x1.z * qscale); a[7] = f2bf(x1.w * qscale);
      bq[h] = a;
    }
  };

  // all-ones A-fragment for the l-accumulating MFMA (bf16 1.0 = 0x3F80)
  bf16x8 ones;
#pragma unroll
  for (int j = 0; j < 8; ++j) ones[j] = (short)0x3F80;

  int qt = qtA;
  int qg = qt * QBLK + wave * 16 + lc;
  bf16x8 bq[2];
  loadQ(qg, bq);

  f32x4 o[4], lsum = (f32x4){0.f, 0.f, 0.f, 0.f};
#pragma unroll
  for (int dt = 0; dt < 4; ++dt) o[dt] = (f32x4){0.f, 0.f, 0.f, 0.f};
  float m = -10000.0f;

  int cur = 0;
  stageK(0, 0);
  __syncthreads();

  for (int it = 0; it < nTot; ++it) {
    const int kt = (it < nA) ? it : it - nA;

    // ---- V fragments for this tile: direct global -> regs (L2-resident;
    //      consumed ~300cy later after QK^T+softmax) ----
    bf16x8 vf[2][4];
#pragma unroll
    for (int t2 = 0; t2 < 2; ++t2)
#pragma unroll
      for (int dt = 0; dt < 4; ++dt)
        vf[t2][dt] = *(const bf16x8*)(vb[dt] + kt * 128 + t2 * 64);

    // ---- stage next K tile ----
    if (it + 1 < nTot) {
      int nkt = (it + 1 < nA) ? it + 1 : it + 1 - nA;
      stageK(nkt, cur ^ 1);
    }

    const char* Kc = (const char*)Kbuf[cur];

    // ---- swapped QK^T: s[t][i] = S[q=qg][k = kb+t*16+g*4+i] ----
    f32x4 s[4];
    __builtin_amdgcn_s_setprio(1);
#pragma unroll
    for (int t = 0; t < 4; ++t) {
      bf16x8 ak0 = *(const bf16x8*)(Kc + ka[t][0]);
      bf16x8 ak1 = *(const bf16x8*)(Kc + ka[t][1]);
      f32x4 z = (f32x4){0.f, 0.f, 0.f, 0.f};
      z = MFMA32K(ak0, bq[0], z);
      z = MFMA32K(ak1, bq[1], z);
      s[t] = z;
    }
    __builtin_amdgcn_s_setprio(0);

    if (kt == qt) {  // causal mask on diagonal tile only
      const int kb = kt * KBLK;
#pragma unroll
      for (int t = 0; t < 4; ++t)
#pragma unroll
        for (int i = 0; i < 4; ++i) {
          int kg = kb + t * 16 + g * 4 + i;
          if (kg > qg) s[t][i] = -30000.0f;
        }
    }

    // ---- in-register online softmax (exp2 domain), defer-max THR=8 ----
    float pmax = fmaxf(fmaxf(s[0][0], s[0][1]), fmaxf(s[0][2], s[0][3]));
#pragma unroll
    for (int t = 1; t < 4; ++t)
      pmax = fmaxf(pmax, fmaxf(fmaxf(s[t][0], s[t][1]),
                               fmaxf(s[t][2], s[t][3])));
    pmax = xred_max(pmax);
    if (!__all(pmax - m <= 8.0f)) {
      float mnew = fmaxf(m, pmax);
      float alpha = EXP2(m - mnew);
      lsum[0] *= alpha;  // only [0] is ever read
#pragma unroll
      for (int dt = 0; dt < 4; ++dt) o[dt] *= alpha;
      m = mnew;
    }
#pragma unroll
    for (int t = 0; t < 4; ++t)
#pragma unroll
      for (int i = 0; i < 4; ++i) s[t][i] = EXP2(s[t][i] - m);

    // ---- pack P; PV + l via MFMA (ones-column) with reg-resident V ----
    union { unsigned uu[4]; bf16x8 v; } pb[2];
#pragma unroll
    for (int t2 = 0; t2 < 2; ++t2) {
      pb[t2].uu[0] = pk_bf16(s[2 * t2][0], s[2 * t2][1]);
      pb[t2].uu[1] = pk_bf16(s[2 * t2][2], s[2 * t2][3]);
      pb[t2].uu[2] = pk_bf16(s[2 * t2 + 1][0], s[2 * t2 + 1][1]);
      pb[t2].uu[3] = pk_bf16(s[2 * t2 + 1][2], s[2 * t2 + 1][3]);
    }
    __builtin_amdgcn_s_setprio(1);
#pragma unroll
    for (int t2 = 0; t2 < 2; ++t2) {
      lsum = MFMA32K(ones, pb[t2].v, lsum);
#pragma unroll
      for (int dt = 0; dt < 4; ++dt)
        o[dt] = MFMA32K(vf[t2][dt], pb[t2].v, o[dt]);
    }
    __builtin_amdgcn_s_setprio(0);

    __syncthreads();  // next K tile landed (vmcnt) + cur fully consumed
    cur ^= 1;

    // ---- phase switch: write q-tile A, reset for q-tile B ----
    if (it == nA - 1) {
      const float inv = 1.0f / lsum[0];
      float* op = O + base + (size_t)qg * Dn;
#pragma unroll
      for (int dt = 0; dt < 4; ++dt) {
        f32x4 r = o[dt] * inv;
        *(f32x4*)(op + dt * 16 + g * 4) = r;
      }
      qt = qtB;
      qg = qt * QBLK + wave * 16 + lc;
      loadQ(qg, bq);
#pragma unroll
      for (int dt = 0; dt < 4; ++dt) o[dt] = (f32x4){0.f, 0.f, 0.f, 0.f};
      lsum = (f32x4){0.f, 0.f, 0.f, 0.f};
      m = -10000.0f;
    }
  }

  // ---- epilogue: q-tile B ----
  const float inv = 1.0f / lsum[0];
  float* op = O + base + (size_t)qg * Dn;
#pragma unroll
  for (int dt = 0; dt < 4; ++dt) {
    f32x4 r = o[dt] * inv;
    *(f32x4*)(op + dt * 16 + g * 4) = r;
  }
}

extern "C" void kernel_launch(void* const* d_in, const int* in_sizes, int n_in,
                              void* d_out, int out_size, void* d_ws, size_t ws_size,
                              hipStream_t stream) {
  const float* Q = (const float*)d_in[0];
  const float* K = (const float*)d_in[1];
  const float* V = (const float*)d_in[2];
  const float* SF = (const float*)d_in[3];
  // d_in[4] causal mask: tril by construction -> applied analytically (k<=q).
  float* O = (float*)d_out;

  short* Kb = (short*)d_ws;  // [B*H][2048][64] bf16
  short* Vt = Kb + NE;       // [B*H][64][2048] bf16 (column-permuted per tile)

  prep<<<dim3(Sn / 64, Bsz * Hn, 2), 256, 0, stream>>>(K, V, Kb, Vt);
  attn_fwd<<<dim3(Bsz * Hn, 16), 256, 0, stream>>>(Q, Kb, Vt, SF, O);
}

// Round 11
// 48.771 us; speedup vs baseline: 1.6811x; 1.6811x over previous
//
#include <hip/hip_runtime.h>
#include <hip/hip_bf16.h>

// Causal attention, B=2 H=16 S=2048 D=64, fp32 in/out.
// R11 = R9 (best: 44us main) + issue-count surgery (kernel is instruction-
// issue-bound: ~400 issue-cy/visit/wave x 4 waves/SIMD x 66 visits/CU):
//  (1) diagonal tile peeled -> branch/mask-free main loop,
//  (2) defer-max gate uses per-lane max; cross-lane xred only when rescale
//      fires (rare at THR=8),
//  (3) max3-shaped max tree (v_max3 fusion).
// Swapped QK^T, in-register softmax (native exp2, defer-max), MFMA l-sum
// (ones column), permuted-V^T zero-conflict b128 PV, permlane reduce,
// setprio, 2-phase double-buffered global_load_lds staging, heavy-first.

typedef __attribute__((ext_vector_type(8))) short bf16x8;
typedef __attribute__((ext_vector_type(4))) float f32x4;
typedef unsigned uint2v __attribute__((ext_vector_type(2)));

#define MFMA32K(a, b, c) __builtin_amdgcn_mfma_f32_16x16x32_bf16(a, b, c, 0, 0, 0)

constexpr int Bsz = 2, Hn = 16, Sn = 2048, Dn = 64;
constexpr int QBLK = 64, KBLK = 64;
constexpr int NE = Bsz * Hn * Sn * Dn;

#if defined(__has_builtin)
#if __has_builtin(__builtin_amdgcn_exp2f)
#define EXP2(x) __builtin_amdgcn_exp2f(x)
#endif
#endif
#ifndef EXP2
#define EXP2(x) exp2f(x)
#endif

__device__ inline short f2bf(float f) {
  union { float f; unsigned u; } v;
  v.f = f;
  unsigned r = v.u + 0x7FFF + ((v.u >> 16) & 1);  // RNE
  return (short)(r >> 16);
}

__device__ inline unsigned pk_bf16(float lo, float hi) {
  unsigned r;
  asm("v_cvt_pk_bf16_f32 %0, %1, %2" : "=v"(r) : "v"(lo), "v"(hi));
  return r;
}

__device__ inline void gl2lds16(const void* g, void* l) {
  __builtin_amdgcn_global_load_lds(
      (const __attribute__((address_space(1))) unsigned int*)g,
      (__attribute__((address_space(3))) unsigned int*)l, 16, 0, 0);
}

// tile rows = 128B; XOR 16B-slot index with row&7 (involution, both sides)
__device__ inline int swz(int row, int colbyte) {
  return row * 128 + (colbyte ^ ((row & 7) << 4));
}

#if defined(__has_builtin)
#if __has_builtin(__builtin_amdgcn_permlane16_swap) && \
    __has_builtin(__builtin_amdgcn_permlane32_swap)
#define HAVE_PERMLANE_SWAP 1
#endif
#endif

__device__ inline float xred_max(float x) {
#ifdef HAVE_PERMLANE_SWAP
  uint2v a = __builtin_amdgcn_permlane16_swap(__float_as_uint(x),
                                              __float_as_uint(x), false, false);
  x = fmaxf(__uint_as_float(a[0]), __uint_as_float(a[1]));
  uint2v b = __builtin_amdgcn_permlane32_swap(__float_as_uint(x),
                                              __float_as_uint(x), false, false);
  x = fmaxf(__uint_as_float(b[0]), __uint_as_float(b[1]));
#else
  x = fmaxf(x, __shfl_xor(x, 16, 64));
  x = fmaxf(x, __shfl_xor(x, 32, 64));
#endif
  return x;
}

// ------- prepass (merged): z=0: K fp32->bf16; z=1: V -> V^T bf16 -------
// V^T columns permuted within each 64-tile: position p holds element
// k(p) = 32*(p>>5) + 16*((p>>2)&1) + 4*((p>>3)&3) + (p&3), so the PV
// A-fragment {k=32t2+4g+i} u {k=32t2+16+4g+i} is contiguous 16B at p=32t2+8g.
__global__ __launch_bounds__(256) void prep(const float* __restrict__ K,
                                            const float* __restrict__ V,
                                            short* __restrict__ Kb,
                                            short* __restrict__ Vt) {
  const int tile = blockIdx.x, bh = blockIdx.y;
  const int tid = threadIdx.x;
  const int r = tid >> 2, c = (tid & 3) * 16;
  const size_t base = (size_t)bh * Sn * Dn;

  if (blockIdx.z == 0) {
    const float* kp = K + base + (size_t)(tile * 64 + r) * Dn + c;
    float4 x0 = *(const float4*)(kp + 0);
    float4 x1 = *(const float4*)(kp + 4);
    float4 x2 = *(const float4*)(kp + 8);
    float4 x3 = *(const float4*)(kp + 12);
    bf16x8 w0, w1;
    w0[0] = f2bf(x0.x); w0[1] = f2bf(x0.y); w0[2] = f2bf(x0.z); w0[3] = f2bf(x0.w);
    w0[4] = f2bf(x1.x); w0[5] = f2bf(x1.y); w0[6] = f2bf(x1.z); w0[7] = f2bf(x1.w);
    w1[0] = f2bf(x2.x); w1[1] = f2bf(x2.y); w1[2] = f2bf(x2.z); w1[3] = f2bf(x2.w);
    w1[4] = f2bf(x3.x); w1[5] = f2bf(x3.y); w1[6] = f2bf(x3.z); w1[7] = f2bf(x3.w);
    short* op = Kb + base + (size_t)(tile * 64 + r) * Dn + c;
    *(bf16x8*)op = w0;
    *(bf16x8*)(op + 8) = w1;
  } else {
    __shared__ short t[64][66];  // +2 pad
    const float* vp = V + base + (size_t)(tile * 64 + r) * Dn + c;
    float4 x0 = *(const float4*)(vp + 0);
    float4 x1 = *(const float4*)(vp + 4);
    float4 x2 = *(const float4*)(vp + 8);
    float4 x3 = *(const float4*)(vp + 12);
    short* tr = &t[r][c];
    tr[0] = f2bf(x0.x); tr[1] = f2bf(x0.y); tr[2] = f2bf(x0.z); tr[3] = f2bf(x0.w);
    tr[4] = f2bf(x1.x); tr[5] = f2bf(x1.y); tr[6] = f2bf(x1.z); tr[7] = f2bf(x1.w);
    tr[8] = f2bf(x2.x); tr[9] = f2bf(x2.y); tr[10] = f2bf(x2.z); tr[11] = f2bf(x2.w);
    tr[12] = f2bf(x3.x); tr[13] = f2bf(x3.y); tr[14] = f2bf(x3.z); tr[15] = f2bf(x3.w);
    __syncthreads();
    short* op = Vt + base + (size_t)r * Sn + tile * 64 + c;
    bf16x8 w0, w1;
#pragma unroll
    for (int j = 0; j < 8; ++j) {
      int p0 = c + j, p1 = c + 8 + j;
      int k0 = 32 * (p0 >> 5) + 16 * ((p0 >> 2) & 1) + 4 * ((p0 >> 3) & 3) + (p0 & 3);
      int k1 = 32 * (p1 >> 5) + 16 * ((p1 >> 2) & 1) + 4 * ((p1 >> 3) & 3) + (p1 & 3);
      w0[j] = t[k0][r];
      w1[j] = t[k1][r];
    }
    *(bf16x8*)op = w0;
    *(bf16x8*)(op + 8) = w1;
  }
}

// ---------------------------- main attention ----------------------------
__global__ __launch_bounds__(256, 4) void attn_fwd(
    const float* __restrict__ Q, const short* __restrict__ Kb,
    const short* __restrict__ Vt, const float* __restrict__ SF,
    float* __restrict__ O) {
  __shared__ short Kbuf[2][64 * 64];   // [k][d] bf16, swizzled
  __shared__ short Vbuf[2][64 * 64];   // [d][p(k)] bf16, swizzled

  const int bh = blockIdx.x;
  const int qt = (gridDim.y - 1) - blockIdx.y;  // heavy-first
  const int tid = threadIdx.x;
  const int wave = tid >> 6, lane = tid & 63;
  const int g = lane >> 4, lc = lane & 15;
  const float qscale = 1.4426950408889634f / SF[0];  // exp2 domain

  const size_t base = (size_t)bh * Sn * Dn;
  const int qg = qt * QBLK + wave * 16 + lc;  // this lane's q row

  // hoisted per-lane fragment LDS offsets (loop-invariant)
  int ka[4][2], va[2][4];
#pragma unroll
  for (int t = 0; t < 4; ++t) {
    ka[t][0] = swz(t * 16 + lc, g * 16);
    ka[t][1] = swz(t * 16 + lc, g * 16 + 64);
  }
#pragma unroll
  for (int t2 = 0; t2 < 2; ++t2)
#pragma unroll
    for (int dt = 0; dt < 4; ++dt)
      va[t2][dt] = swz(dt * 16 + lc, t2 * 64 + g * 16);
  // hoisted staging source offsets (within a tile)
  int koff[2], voff[2];
#pragma unroll
  for (int j = 0; j < 2; ++j) {
    int c = wave * 2 + j;
    int off = c * 1024 + lane * 16;
    int row = off >> 7;
    int col = (off & 127) ^ ((row & 7) << 4);
    koff[j] = row * 128 + col;
    voff[j] = row * (Sn * 2) + col;
  }

  const char* kpg = (const char*)(Kb + base);
  const char* vpg = (const char*)(Vt + base);

  auto stageK = [&](int buf) {
#pragma unroll
    for (int j = 0; j < 2; ++j)
      gl2lds16(kpg + koff[j], (char*)Kbuf[buf] + (wave * 2 + j) * 1024);
    kpg += KBLK * Dn * 2;
  };
  auto stageV = [&](int buf) {
#pragma unroll
    for (int j = 0; j < 2; ++j)
      gl2lds16(vpg + voff[j], (char*)Vbuf[buf] + (wave * 2 + j) * 1024);
    vpg += KBLK * 2;
  };

  // ---- Q fragment (B operand): elem j = Q[qg][g*8+32h+j] * qscale ----
  bf16x8 bq[2];
  {
    const float* qp = Q + base + (size_t)qg * Dn + g * 8;
#pragma unroll
    for (int h = 0; h < 2; ++h) {
      float4 x0 = *(const float4*)(qp + 32 * h);
      float4 x1 = *(const float4*)(qp + 32 * h + 4);
      bf16x8 a;
      a[0] = f2bf(x0.x * qscale); a[1] = f2bf(x0.y * qscale);
      a[2] = f2bf(x0.z * qscale); a[3] = f2bf(x0.w * qscale);
      a[4] = f2bf(x1.x * qscale); a[5] = f2bf(x1.y * qscale);
      a[6] = f2bf(x1.z * qscale); a[7] = f2bf(x1.w * qscale);
      bq[h] = a;
    }
  }

  // all-ones A-fragment for the l-accumulating MFMA (bf16 1.0 = 0x3F80)
  bf16x8 ones;
#pragma unroll
  for (int j = 0; j < 8; ++j) ones[j] = (short)0x3F80;

  f32x4 o[4], lsum = (f32x4){0.f, 0.f, 0.f, 0.f};
#pragma unroll
  for (int dt = 0; dt < 4; ++dt) o[dt] = (f32x4){0.f, 0.f, 0.f, 0.f};
  float m = -10000.0f;  // finite sentinel; first tile always rescales

  int cur = 0;
  stageK(0);
  stageV(0);
  __syncthreads();

  // shared per-tile body; MASKED=true only for the peeled diagonal tile
  auto tile_body = [&](int cur_, bool stage_next, bool masked, int kb) {
    const char* Kc = (const char*)Kbuf[cur_];
    const char* Vc = (const char*)Vbuf[cur_];

    // ---- swapped QK^T: s[t][i] = S[q=qg][k = kb+t*16+g*4+i] ----
    f32x4 s[4];
    __builtin_amdgcn_s_setprio(1);
#pragma unroll
    for (int t = 0; t < 4; ++t) {
      bf16x8 ak0 = *(const bf16x8*)(Kc + ka[t][0]);
      bf16x8 ak1 = *(const bf16x8*)(Kc + ka[t][1]);
      f32x4 z = (f32x4){0.f, 0.f, 0.f, 0.f};
      z = MFMA32K(ak0, bq[0], z);
      z = MFMA32K(ak1, bq[1], z);
      s[t] = z;
    }
    __builtin_amdgcn_s_setprio(0);

    if (masked) {
#pragma unroll
      for (int t = 0; t < 4; ++t)
#pragma unroll
        for (int i = 0; i < 4; ++i) {
          int kg = kb + t * 16 + g * 4 + i;
          if (kg > qg) s[t][i] = -30000.0f;
        }
    }

    // ---- softmax (exp2 domain), defer-max THR=8 with LOCAL gate ----
    // max3-shaped tree over this lane's 16 values
    float a0 = fmaxf(fmaxf(s[0][0], s[0][1]), s[0][2]);
    float a1 = fmaxf(fmaxf(s[0][3], s[1][0]), s[1][1]);
    float a2 = fmaxf(fmaxf(s[1][2], s[1][3]), s[2][0]);
    float a3 = fmaxf(fmaxf(s[2][1], s[2][2]), s[2][3]);
    float a4 = fmaxf(fmaxf(s[3][0], s[3][1]), s[3][2]);
    float b0 = fmaxf(fmaxf(a0, a1), a2);
    float b1 = fmaxf(fmaxf(a3, a4), s[3][3]);
    float plocal = fmaxf(b0, b1);
    if (!__all(plocal - m <= 8.0f)) {
      float pmax = xred_max(plocal);     // row max (only when rescaling)
      float mnew = fmaxf(m, pmax);
      float alpha = EXP2(m - mnew);
      lsum[0] *= alpha;  // only [0] is ever read
#pragma unroll
      for (int dt = 0; dt < 4; ++dt) o[dt] *= alpha;
      m = mnew;
    }
#pragma unroll
    for (int t = 0; t < 4; ++t)
#pragma unroll
      for (int i = 0; i < 4; ++i) s[t][i] = EXP2(s[t][i] - m);

    // ---- pack P; PV + l via MFMA (ones-column), zero-conflict b128 ----
    union { unsigned uu[4]; bf16x8 v; } pb[2];
#pragma unroll
    for (int t2 = 0; t2 < 2; ++t2) {
      pb[t2].uu[0] = pk_bf16(s[2 * t2][0], s[2 * t2][1]);
      pb[t2].uu[1] = pk_bf16(s[2 * t2][2], s[2 * t2][3]);
      pb[t2].uu[2] = pk_bf16(s[2 * t2 + 1][0], s[2 * t2 + 1][1]);
      pb[t2].uu[3] = pk_bf16(s[2 * t2 + 1][2], s[2 * t2 + 1][3]);
    }
    __builtin_amdgcn_s_setprio(1);
#pragma unroll
    for (int t2 = 0; t2 < 2; ++t2) {
      lsum = MFMA32K(ones, pb[t2].v, lsum);
#pragma unroll
      for (int dt = 0; dt < 4; ++dt) {
        bf16x8 av = *(const bf16x8*)(Vc + va[t2][dt]);
        o[dt] = MFMA32K(av, pb[t2].v, o[dt]);
      }
    }
    __builtin_amdgcn_s_setprio(0);

    __syncthreads();  // next tile landed (vmcnt) + cur fully consumed
  };

  // ---- main loop: kt = 0..qt-1, branch/mask-free ----
  for (int kt = 0; kt < qt; ++kt) {
    stageK(cur ^ 1);             // stage tile kt+1 (kt+1 <= qt always here)
    stageV(cur ^ 1);
    tile_body(cur, true, false, 0);
    cur ^= 1;
  }
  // ---- peeled diagonal tile (kt == qt): mask active, no next stage ----
  tile_body(cur, false, true, qt * KBLK);

  // ---- epilogue: O[q][d] = o / l, coalesced f32x4 stores ----
  const float inv = 1.0f / lsum[0];
  float* op = O + base + (size_t)qg * Dn;
#pragma unroll
  for (int dt = 0; dt < 4; ++dt) {
    f32x4 r = o[dt] * inv;
    *(f32x4*)(op + dt * 16 + g * 4) = r;
  }
}

extern "C" void kernel_launch(void* const* d_in, const int* in_sizes, int n_in,
                              void* d_out, int out_size, void* d_ws, size_t ws_size,
                              hipStream_t stream) {
  const float* Q = (const float*)d_in[0];
  const float* K = (const float*)d_in[1];
  const float* V = (const float*)d_in[2];
  const float* SF = (const float*)d_in[3];
  // d_in[4] causal mask: tril by construction -> applied analytically (k<=q).
  float* O = (float*)d_out;

  short* Kb = (short*)d_ws;  // [B*H][2048][64] bf16
  short* Vt = Kb + NE;       // [B*H][64][2048] bf16 (column-permuted per tile)

  prep<<<dim3(Sn / 64, Bsz * Hn, 2), 256, 0, stream>>>(K, V, Kb, Vt);
  attn_fwd<<<dim3(Bsz * Hn, Sn / QBLK), 256, 0, stream>>>(Q, Kb, Vt, SF, O);
}